// Round 5
// baseline (239.403 us; speedup 1.0000x reference)
//
#include <hip/hip_runtime.h>
#include <math.h>

// HiddenLayer_20126216749058: sparse-GP layer, N=1024, Q=32, M=256, D=32.
// R11 (resubmit; previous attempt died to container-acquire infra failure).
// Launch-depth 5->4. Kinv (3-term NS) moved into kA: E = sKM-I computed
// DIRECTLY from Z (no KM materialization; E tiny ~1e-2, bf16 panels for
// G=E@E MFMA are 2nd-order safe); abf/t3 move to kB; W1/Y2T/fmean/V to
// kE; kD deleted. KM array + Kmm blocks + seg3 deleted (S4 = sum e^2
// accumulated per-NS-tile into ep2[10], summed at finalize).

#define N_PTS 1024
#define QD 32
#define MI 256
#define DOUT 32
#define JITTER 1e-6f
#define LOG2E 1.4426950408889634f
#define LSU 40    // bf16 LDS row stride (80B)

typedef short short8 __attribute__((ext_vector_type(8)));
typedef float floatx4 __attribute__((ext_vector_type(4)));
typedef unsigned short ushort;

// ---- workspace layout (float offsets) ----
#define OFF_PSI2S 0           // 65536 zeroed (atomic)
#define OFF_SCOV  65536       // 65536 zeroed (atomic)
#define OFF_GA    131072      // 65536 zeroed (atomic)
#define OFF_S     196608      // 16 scalars zeroed; [8] = done-counter
#define ZERO_CNT  196624
#define OFF_PSI1  196624      // 262144 N*M fp32
#define OFF_P1H   458768      // 131072 N*M bf16
#define OFF_GM    589840      // 262144 N*M fp32 (LOG2E-scaled)
#define OFF_F2    851984      // 32768  N*Q fp32 (LOG2E-scaled)
#define OFF_EP2   884752      // 16     per-NS-tile sum e^2 (plain stores)
#define OFF_KINV  950288      // 65536
#define OFF_KH    1015824     // 32768  M*M bf16
#define OFF_W1    1048592     // 65536  Kinv@psi2s
#define OFF_W     1114128     // 65536  Y2T = Scov@Kinv
#define OFF_T3    1179664     // 8192   M*D
#define OFF_ZB    1187856     // 4096   M*Q bf16
#define OFF_ABF   1191952     // 131072 N*M bf16
#define OFF_ABFT  1323024     // 131072 M*N bf16
#define OFF_BTJ   1454096     // 1048576 D*M*M bf16 [d][j][l]
#define OFF_BTL   2502672     // 1048576 D*M*M bf16 [d][l][j]
#define OFF_TMP   3551248     // 4194304 N*D*M bf16 [n][d][l]
#define OFF_V     7745552     // 8192   M*D = psi2s@t3
// end = 7753744 floats = 31.0 MB

struct Params {
  const float *Xm, *Xv, *Z, *ls, *pvar, *pbeta, *qmu, *qs;
  float *psi1, *gm, *f2, *Kinv, *W1, *W, *t3, *V, *ep2;
  float *psi2s, *Scov, *GA, *Sv, *zarea;
  ushort *p1h, *Kh, *zb, *abf, *abfT, *Btj, *Btl, *tmp;
  float *outMean, *outVar, *outL;
};

__device__ __forceinline__ ushort f2bf(float x) {
  unsigned int u = __builtin_bit_cast(unsigned int, x);
  u += 0x7fffu + ((u >> 16) & 1u);
  return (ushort)(u >> 16);
}

// upper-triangular 4x4 tile enumeration: t in [0,10) -> (a,b), a<=b
__device__ __forceinline__ void tile_ab(int t, int* a_, int* b_) {
  int a = (t >= 4) + (t >= 7) + (t >= 9);
  int st = (a == 0) ? 0 : (a == 1) ? 4 : (a == 2) ? 7 : 9;
  *a_ = a; *b_ = t - st + a;
}

// ================= Phase A =================
// [0,256) stats 4n/blk | [256,266) NS Kinv direct-E | [266,363) zero
// [363,371) zb | [371,1395) btj | [1395,2419) btl
__global__ __launch_bounds__(256) void kA(Params p) {
  __shared__ __align__(16) float sb[4160];
  int bx = blockIdx.x, tid = threadIdx.x;
  if (bx < 256) {
    int nb = bx*4;
    float* w1s  = sb;        // [4][32]
    float* w1mu = sb+128;
    float* w2s  = sb+256;
    float* w2mu = sb+384;
    float* x1a  = sb+512;    // la1+a1s
    float* x2a  = sb+640;    // 0.5*la2+a2s
    float* rl2s = sb+768;    // [32]
    float* csh  = sb+800;    // [8]: c1sh[4], c2sh[4]
    float v = *p.pvar;
    if (tid < 128) {
      int nl = tid >> 5, q = tid & 31;
      int n = nb + nl;
      float s = p.Xv[n*QD+q], mu = p.Xm[n*QD+q], l = p.ls[q], l2 = l*l;
      float rl2 = 1.f/l2;
      float d1 = l2 + s, d2 = l2 + 2.f*s;
      float iw1 = 1.f/d1, iw2 = 1.f/d2;
      w1s[nl*32+q] = iw1; w1mu[nl*32+q] = iw1*mu;
      w2s[nl*32+q] = iw2; w2mu[nl*32+q] = iw2*mu;
      x1a[nl*32+q] = logf(d1*rl2) + mu*mu*iw1;
      x2a[nl*32+q] = 0.5f*logf(d2*rl2) + mu*mu*iw2;
      if (nl == 0) rl2s[q] = rl2;
      p.f2[n*QD+q] = LOG2E*0.5f*(rl2 - iw2);
    }
    __syncthreads();
    {
      int w = tid >> 6, lane = tid & 63;
      float x1 = (lane < 32) ? x1a[w*32+lane] : 0.f;
      float x2 = (lane < 32) ? x2a[w*32+lane] : 0.f;
      #pragma unroll
      for (int o = 16; o >= 1; o >>= 1) {
        x1 += __shfl_xor(x1, o, 32);
        x2 += __shfl_xor(x2, o, 32);
      }
      if (lane == 0) { csh[w] = -0.5f*x1; csh[4+w] = 2.f*logf(v) - x2; }
    }
    __syncthreads();
    int m = tid;
    float zv[32];
    float zsq = 0;
    #pragma unroll
    for (int q4 = 0; q4 < QD; q4 += 4) {
      float4 z4 = *(const float4*)&p.Z[m*QD + q4];
      zv[q4+0]=z4.x; zv[q4+1]=z4.y; zv[q4+2]=z4.z; zv[q4+3]=z4.w;
      zsq += rl2s[q4+0]*z4.x*z4.x + rl2s[q4+1]*z4.y*z4.y
           + rl2s[q4+2]*z4.z*z4.z + rl2s[q4+3]*z4.w*z4.w;
    }
    #pragma unroll
    for (int nl = 0; nl < 4; nl++) {
      int n = nb + nl;
      float b1 = 0, c1a = 0, eb = 0, ec = 0;
      #pragma unroll
      for (int q = 0; q < QD; q++) {
        float z = zv[q], zz = z*z;
        b1 += w1mu[nl*32+q]*z; c1a += w1s[nl*32+q]*zz;
        eb += w2mu[nl*32+q]*z; ec += w2s[nl*32+q]*zz;
      }
      float pv = v * __expf(csh[nl] + b1 - 0.5f*c1a);
      p.psi1[n*MI + m] = pv;
      p.p1h[n*MI + m] = f2bf(pv);
      p.gm[n*MI + m] = LOG2E*(0.5f*csh[4+nl] + (eb - 0.25f*ec) - 0.25f*zsq);
    }
  } else if (bx < 266) {
    // NS Kinv = s(I - E + E@E), E computed from Z directly (no KM array).
    // 10 upper 64x64 tiles; G=E@E via bf16 LDS panels + MFMA; mirror stores.
    int t = bx - 256;
    int a, b; tile_ab(t, &a, &b);
    int i0 = a*64, j0 = b*64;
    ushort* Ei = (ushort*)sb;            // [64][LSU] bf16 = 1280 fl
    ushort* Ej = (ushort*)(sb + 1280);   // [64][LSU] bf16
    float* zsq = sb + 2560;              // [256]
    float* rl2 = sb + 2816;              // [32]
    float* wred = sb + 2944;             // [4]
    float v = *p.pvar;
    float s = 1.f/(v + JITTER);
    float sv = s*v;
    float dterm = 1.f - s*JITTER;
    if (tid < 32) { float l = p.ls[tid]; rl2[tid] = 1.f/(l*l); }
    __syncthreads();
    {
      int m = tid;
      float acc = 0;
      #pragma unroll
      for (int q4 = 0; q4 < 32; q4 += 4) {
        float4 z4 = *(const float4*)&p.Z[m*32 + q4];
        acc += z4.x*z4.x*rl2[q4] + z4.y*z4.y*rl2[q4+1]
             + z4.z*z4.z*rl2[q4+2] + z4.w*z4.w*rl2[q4+3];
      }
      zsq[m] = acc;
    }
    __syncthreads();
    int rowIdx = tid >> 1;           // [0,128)
    int pan = rowIdx >> 6;           // 0: i-block, 1: j-block
    int rl_ = rowIdx & 63;
    int rg = (pan ? j0 : i0) + rl_;
    int khalf = (tid & 1)*16;
    float ziw[32];
    #pragma unroll
    for (int q4 = 0; q4 < 32; q4 += 4) {
      float4 z4 = *(const float4*)&p.Z[rg*32 + q4];
      ziw[q4] = z4.x*rl2[q4]; ziw[q4+1] = z4.y*rl2[q4+1];
      ziw[q4+2] = z4.z*rl2[q4+2]; ziw[q4+3] = z4.w*rl2[q4+3];
    }
    float zsq_r = zsq[rg];
    ushort* mypan = (pan ? Ej : Ei) + rl_*LSU + khalf;
    int lane = tid & 63, w = tid >> 6, l15 = lane & 15, quad = lane >> 4;
    floatx4 accs[4];
    #pragma unroll
    for (int c = 0; c < 4; c++) accs[c] = (floatx4){0.f,0.f,0.f,0.f};
    for (int kc = 0; kc < 256; kc += 32) {
      __syncthreads();
      #pragma unroll 4
      for (int kk = 0; kk < 16; kk++) {
        int kgl = kc + khalf + kk;
        float dot = 0;
        #pragma unroll
        for (int q4 = 0; q4 < 32; q4 += 4) {
          float4 zk = *(const float4*)&p.Z[kgl*32 + q4];
          dot += ziw[q4]*zk.x + ziw[q4+1]*zk.y + ziw[q4+2]*zk.z + ziw[q4+3]*zk.w;
        }
        float e = sv*__expf(-0.5f*(zsq_r + zsq[kgl] - 2.f*dot));
        if (rg == kgl) e -= dterm;
        mypan[kk] = f2bf(e);
      }
      __syncthreads();
      short8 af = *(const short8*)&Ei[(w*16 + l15)*LSU + quad*8];
      #pragma unroll
      for (int c = 0; c < 4; c++) {
        short8 bf_ = *(const short8*)&Ej[(c*16 + l15)*LSU + quad*8];
        accs[c] = __builtin_amdgcn_mfma_f32_16x16x32_bf16(af, bf_, accs[c], 0, 0, 0);
      }
    }
    // epilogue: recompute e-tile (fp32), Kinv = s(delta - e + G), ep2 partial
    float e2sum = 0;
    #pragma unroll
    for (int c = 0; c < 4; c++) {
      int J = j0 + c*16 + l15;
      #pragma unroll
      for (int r = 0; r < 4; r++) {
        int I = i0 + w*16 + quad*4 + r;
        float dot = 0;
        #pragma unroll
        for (int q4 = 0; q4 < 32; q4 += 4) {
          float4 zi = *(const float4*)&p.Z[I*32 + q4];
          float4 zj = *(const float4*)&p.Z[J*32 + q4];
          dot += rl2[q4]*zi.x*zj.x + rl2[q4+1]*zi.y*zj.y
               + rl2[q4+2]*zi.z*zj.z + rl2[q4+3]*zi.w*zj.w;
        }
        float e = sv*__expf(-0.5f*(zsq[I] + zsq[J] - 2.f*dot));
        if (I == J) e -= dterm;
        e2sum += e*e;
        float kv = s*((I == J ? 1.f : 0.f) - e + accs[c][r]);
        p.Kinv[I*MI + J] = kv;
        ushort kh = f2bf(kv);
        p.Kh[I*MI + J] = kh;
        if (i0 != j0) { p.Kinv[J*MI + I] = kv; p.Kh[J*MI + I] = kh; }
      }
    }
    #pragma unroll
    for (int off = 32; off >= 1; off >>= 1) e2sum += __shfl_down(e2sum, off, 64);
    __syncthreads();
    if (lane == 0) wred[w] = e2sum;
    __syncthreads();
    if (tid == 0) p.ep2[t] = wred[0] + wred[1] + wred[2] + wred[3];
  } else if (bx < 363) {
    int base = (bx - 266)*2048 + tid*8;
    #pragma unroll
    for (int e = 0; e < 8; e++) {
      int i = base + e;
      if (i < ZERO_CNT) p.zarea[i] = 0.f;
    }
  } else if (bx < 371) {
    int i = ((bx - 363)*256 + tid)*4;
    float4 z = *(const float4*)&p.Z[i];
    uint2 o;
    o.x = (unsigned)f2bf(z.x) | ((unsigned)f2bf(z.y) << 16);
    o.y = (unsigned)f2bf(z.z) | ((unsigned)f2bf(z.w) << 16);
    *(uint2*)&p.zb[i] = o;
  } else if (bx < 1395) {
    int idx = bx - 371;
    int j = idx & 255, l0 = (idx >> 8)*64;
    int base = j*8192 + l0*32;
    #pragma unroll
    for (int e = 0; e < 8; e++) {
      int lin = e*256 + tid;
      sb[(lin >> 5)*33 + (lin & 31)] = p.qs[base + lin];
    }
    __syncthreads();
    int ll = tid & 63, kq = tid >> 6;
    int l = l0 + ll;
    #pragma unroll
    for (int w8 = 0; w8 < 8; w8++) {
      int k = kq*8 + w8;
      float v = (l <= j) ? sb[ll*33 + k] : 0.f;
      p.Btj[k*65536 + j*256 + l] = f2bf(v);
    }
  } else {
    int idx = bx - 1395;
    int l = idx & 255, j0 = (idx >> 8)*64;
    {
      int jr = tid >> 2, d8 = (tid & 3)*8;
      const float* src = &p.qs[(j0+jr)*8192 + l*32 + d8];
      float4 a = *(const float4*)src, b = *(const float4*)(src+4);
      float* dst = &sb[jr*33 + d8];
      dst[0]=a.x; dst[1]=a.y; dst[2]=a.z; dst[3]=a.w;
      dst[4]=b.x; dst[5]=b.y; dst[6]=b.z; dst[7]=b.w;
    }
    __syncthreads();
    int d = tid >> 3, j8 = (tid & 7)*8;
    unsigned int pk[4];
    #pragma unroll
    for (int q = 0; q < 4; q++) {
      int ja = j0 + j8 + q*2;
      float va = (l <= ja)   ? sb[(j8 + q*2)*33 + d]     : 0.f;
      float vb = (l <= ja+1) ? sb[(j8 + q*2 + 1)*33 + d] : 0.f;
      pk[q] = (unsigned)f2bf(va) | ((unsigned)f2bf(vb) << 16);
    }
    *(uint4*)&p.Btl[d*65536 + l*256 + j0 + j8] = make_uint4(pk[0], pk[1], pk[2], pk[3]);
  }
}

// ================= Phase B =================
// [0,320) psi2 upper tiles | [320,480) scov (10 t x 16 d-grp of 2)
// [480,544) abf = p1h@Kh | [544,576) t3 = Kinv@qmu
__global__ __launch_bounds__(256) void kB(Params p) {
  __shared__ __align__(16) float sb[4160];
  int bx = blockIdx.x, tid = threadIdx.x;
  int lane = tid & 63, w = tid >> 6, l15 = lane & 15, quad = lane >> 4;
  if (bx < 320) {
    int t = bx % 10, chunk = bx / 10;
    int a, b; tile_ab(t, &a, &b);
    int tm = a*64, tk = b*64;
    int n0 = chunk*32;
    float zm[8];
    {
      const float* zr = &p.Z[(tm + w*16 + l15)*32 + quad*8];
      float4 aq = *(const float4*)zr, bq = *(const float4*)(zr + 4);
      zm[0]=aq.x; zm[1]=aq.y; zm[2]=aq.z; zm[3]=aq.w;
      zm[4]=bq.x; zm[5]=bq.y; zm[6]=bq.z; zm[7]=bq.w;
    }
    short8 bfr[4];
    #pragma unroll
    for (int c = 0; c < 4; c++)
      bfr[c] = *(const short8*)&p.zb[(tk + c*16 + l15)*32 + quad*8];
    float accs[4][4] = {};
    #pragma unroll 2
    for (int nl = 0; nl < 32; nl++) {
      int n = n0 + nl;
      const float* fp = &p.f2[n*32 + quad*8];
      float4 f0 = *(const float4*)fp, f1 = *(const float4*)(fp + 4);
      unsigned q0 = (unsigned)f2bf(f0.x*zm[0]) | ((unsigned)f2bf(f0.y*zm[1]) << 16);
      unsigned q1 = (unsigned)f2bf(f0.z*zm[2]) | ((unsigned)f2bf(f0.w*zm[3]) << 16);
      unsigned q2 = (unsigned)f2bf(f1.x*zm[4]) | ((unsigned)f2bf(f1.y*zm[5]) << 16);
      unsigned q3 = (unsigned)f2bf(f1.z*zm[6]) | ((unsigned)f2bf(f1.w*zm[7]) << 16);
      uint4 u4 = make_uint4(q0, q1, q2, q3);
      short8 af = __builtin_bit_cast(short8, u4);
      float4 gmv = *(const float4*)&p.gm[n*256 + tm + w*16 + quad*4];
      float gmr[4] = {gmv.x, gmv.y, gmv.z, gmv.w};
      #pragma unroll
      for (int c = 0; c < 4; c++) {
        floatx4 zz = {0.f, 0.f, 0.f, 0.f};
        floatx4 g = __builtin_amdgcn_mfma_f32_16x16x32_bf16(af, bfr[c], zz, 0, 0, 0);
        float gk = p.gm[n*256 + tk + c*16 + l15];
        #pragma unroll
        for (int r = 0; r < 4; r++)
          accs[c][r] += __builtin_exp2f(g[r] + gmr[r] + gk);
      }
    }
    #pragma unroll
    for (int c = 0; c < 4; c++)
      #pragma unroll
      for (int r = 0; r < 4; r++)
        atomicAdd(&p.psi2s[(tm + w*16 + quad*4 + r)*256 + tk + c*16 + l15], accs[c][r]);
    if (tm != tk) {
      #pragma unroll
      for (int c = 0; c < 4; c++)
        #pragma unroll
        for (int r = 0; r < 4; r++)
          sb[(w*16 + quad*4 + r)*65 + c*16 + l15] = accs[c][r];
      __syncthreads();
      #pragma unroll
      for (int c = 0; c < 4; c++)
        #pragma unroll
        for (int r = 0; r < 4; r++)
          atomicAdd(&p.psi2s[(tk + w*16 + quad*4 + r)*256 + tm + c*16 + l15],
                    sb[(c*16 + l15)*65 + (w*16 + quad*4 + r)]);
    }
  } else if (bx < 480) {
    // Scov upper tiles, d-groups of 2, k-loop bounded (Btj[d][i][l]=0 for l>i)
    int idx = bx - 320;
    int t = idx % 10;
    int a, b; tile_ab(t, &a, &b);
    int i0 = a*64, j0 = b*64;
    int d0 = (idx / 10)*2;
    int kend = (a + 1)*64;
    ushort* Au = (ushort*)sb; ushort* Bu = Au + 2560;
    floatx4 accs[4];
    #pragma unroll
    for (int c = 0; c < 4; c++) accs[c] = (floatx4){0.f,0.f,0.f,0.f};
    int sr = tid >> 2, sq = (tid & 3)*8;
    for (int dd = 0; dd < 2; dd++) {
      const ushort* base = p.Btj + (size_t)(d0 + dd)*65536;
      for (int kc = 0; kc < kend; kc += 32) {
        __syncthreads();
        *(uint4*)&Au[sr*LSU + sq] = *(const uint4*)&base[(i0+sr)*256 + kc + sq];
        *(uint4*)&Bu[sr*LSU + sq] = *(const uint4*)&base[(j0+sr)*256 + kc + sq];
        __syncthreads();
        short8 af = *(const short8*)&Au[(w*16 + l15)*LSU + quad*8];
        #pragma unroll
        for (int c = 0; c < 4; c++) {
          short8 bfv = *(const short8*)&Bu[(c*16 + l15)*LSU + quad*8];
          accs[c] = __builtin_amdgcn_mfma_f32_16x16x32_bf16(af, bfv, accs[c], 0, 0, 0);
        }
      }
    }
    #pragma unroll
    for (int c = 0; c < 4; c++)
      #pragma unroll
      for (int r = 0; r < 4; r++)
        atomicAdd(&p.Scov[(i0 + w*16 + quad*4 + r)*256 + j0 + c*16 + l15], accs[c][r]);
    if (i0 != j0) {
      __syncthreads();
      #pragma unroll
      for (int c = 0; c < 4; c++)
        #pragma unroll
        for (int r = 0; r < 4; r++)
          sb[(w*16 + quad*4 + r)*65 + c*16 + l15] = accs[c][r];
      __syncthreads();
      #pragma unroll
      for (int c = 0; c < 4; c++)
        #pragma unroll
        for (int r = 0; r < 4; r++)
          atomicAdd(&p.Scov[(j0 + w*16 + quad*4 + r)*256 + i0 + c*16 + l15],
                    sb[(c*16 + l15)*65 + (w*16 + quad*4 + r)]);
    }
  } else if (bx < 544) {
    // abf = p1h @ Kh (bf16 MFMA)
    int idx = bx - 480;
    int j0 = (idx & 3)*64, n0 = (idx >> 2)*64;
    ushort* Ah = (ushort*)sb; ushort* Bh = Ah + 2560;
    floatx4 acc[4];
    #pragma unroll
    for (int c = 0; c < 4; c++) acc[c] = (floatx4){0.f,0.f,0.f,0.f};
    int sr = tid >> 2, sq = (tid & 3)*8;
    for (int kc = 0; kc < 256; kc += 32) {
      __syncthreads();
      *(uint4*)&Ah[sr*LSU + sq] = *(const uint4*)&p.p1h[(n0+sr)*256 + kc + sq];
      *(uint4*)&Bh[sr*LSU + sq] = *(const uint4*)&p.Kh[(j0+sr)*256 + kc + sq];
      __syncthreads();
      short8 ah = *(const short8*)&Ah[(w*16 + l15)*LSU + quad*8];
      #pragma unroll
      for (int c = 0; c < 4; c++) {
        short8 bh = *(const short8*)&Bh[(c*16 + l15)*LSU + quad*8];
        acc[c] = __builtin_amdgcn_mfma_f32_16x16x32_bf16(ah, bh, acc[c], 0, 0, 0);
      }
    }
    #pragma unroll
    for (int c = 0; c < 4; c++)
      #pragma unroll
      for (int r = 0; r < 4; r++) {
        int n = n0 + w*16 + quad*4 + r, j = j0 + c*16 + l15;
        ushort hv = f2bf(acc[c][r]);
        p.abf[n*256 + j] = hv;
        p.abfT[j*1024 + n] = hv;
      }
  } else {
    // t3 = Kinv @ qmu
    int rbase = (bx - 544)*8;
    int c = tid & 31, r = rbase + (tid >> 5);
    float acc = 0;
    for (int k = 0; k < 256; k += 4) {
      float4 a4 = *(const float4*)&p.Kinv[r*256 + k];
      acc += a4.x*p.qmu[(k+0)*32+c] + a4.y*p.qmu[(k+1)*32+c]
           + a4.z*p.qmu[(k+2)*32+c] + a4.w*p.qmu[(k+3)*32+c];
    }
    p.t3[r*32 + c] = acc;
  }
}

// ================= Phase E =================
// [0,2048) tmp GEMM (l0-interleaved) | [2048,2128) GA gram upper
// [2128,2192) W1 = Kinv@psi2s | [2192,2256) Y2T = Scov@Kinv
// [2256,2384) fmean | [2384,2416) V = psi2s @ t3
__global__ __launch_bounds__(256) void kE(Params p) {
  __shared__ __align__(16) float sb[4160];
  int bx = blockIdx.x, tid = threadIdx.x;
  int lane = tid & 63, w = tid >> 6, l15 = lane & 15, quad = lane >> 4;
  if (bx < 2048) {
    // block map: l0 class from bits >=8 so resident sets mix 8/6/4/2-step blocks
    int u = bx & 255, vv = bx >> 8;
    int n0 = (u & 15)*64;
    int dgl = (u >> 4) | ((vv >> 2) << 4);   // d in [0,32)
    int l0c = vv & 3;
    int c0 = dgl*256 + l0c*64;               // flat col base over (d,l)
    int l0 = l0c*64;                         // cols j<l0 of Btl rows are zero
    ushort* As = (ushort*)sb; ushort* Bs = As + 2560;
    floatx4 acc[4];
    #pragma unroll
    for (int c = 0; c < 4; c++) acc[c] = (floatx4){0.f,0.f,0.f,0.f};
    int sr = tid >> 2, sq = (tid & 3)*8;
    for (int kc = l0; kc < 256; kc += 32) {
      __syncthreads();
      *(uint4*)&As[sr*LSU + sq] = *(const uint4*)&p.abf[(n0+sr)*256 + kc + sq];
      *(uint4*)&Bs[sr*LSU + sq] = *(const uint4*)&p.Btl[(size_t)(c0+sr)*256 + kc + sq];
      __syncthreads();
      short8 af = *(const short8*)&As[(w*16 + l15)*LSU + quad*8];
      #pragma unroll
      for (int c = 0; c < 4; c++) {
        short8 b = *(const short8*)&Bs[(c*16 + l15)*LSU + quad*8];
        acc[c] = __builtin_amdgcn_mfma_f32_16x16x32_bf16(af, b, acc[c], 0, 0, 0);
      }
    }
    #pragma unroll
    for (int c = 0; c < 4; c++)
      #pragma unroll
      for (int r = 0; r < 4; r++) {
        int n = n0 + w*16 + quad*4 + r, cc = c0 + c*16 + l15;
        p.tmp[(size_t)n*8192 + cc] = f2bf(acc[c][r]);
      }
  } else if (bx < 2128) {
    // GA = abf^T abf, symmetric: upper tiles + mirror, 8 n-chunks of 128
    int idx = bx - 2048;
    int t = idx % 10;
    int a, b; tile_ab(t, &a, &b);
    int i0 = a*64, j0 = b*64;
    int nc0 = (idx / 10)*128;
    ushort* Au = (ushort*)sb; ushort* Bu = Au + 2560;
    floatx4 accs[4];
    #pragma unroll
    for (int c = 0; c < 4; c++) accs[c] = (floatx4){0.f,0.f,0.f,0.f};
    int sr = tid >> 2, sq = (tid & 3)*8;
    for (int kc = 0; kc < 128; kc += 32) {
      __syncthreads();
      *(uint4*)&Au[sr*LSU + sq] = *(const uint4*)&p.abfT[(i0+sr)*1024 + nc0 + kc + sq];
      *(uint4*)&Bu[sr*LSU + sq] = *(const uint4*)&p.abfT[(j0+sr)*1024 + nc0 + kc + sq];
      __syncthreads();
      short8 af = *(const short8*)&Au[(w*16 + l15)*LSU + quad*8];
      #pragma unroll
      for (int c = 0; c < 4; c++) {
        short8 bfv = *(const short8*)&Bu[(c*16 + l15)*LSU + quad*8];
        accs[c] = __builtin_amdgcn_mfma_f32_16x16x32_bf16(af, bfv, accs[c], 0, 0, 0);
      }
    }
    #pragma unroll
    for (int c = 0; c < 4; c++)
      #pragma unroll
      for (int r = 0; r < 4; r++)
        atomicAdd(&p.GA[(i0 + w*16 + quad*4 + r)*256 + j0 + c*16 + l15], accs[c][r]);
    if (i0 != j0) {
      __syncthreads();
      #pragma unroll
      for (int c = 0; c < 4; c++)
        #pragma unroll
        for (int r = 0; r < 4; r++)
          sb[(w*16 + quad*4 + r)*65 + c*16 + l15] = accs[c][r];
      __syncthreads();
      #pragma unroll
      for (int c = 0; c < 4; c++)
        #pragma unroll
        for (int r = 0; r < 4; r++)
          atomicAdd(&p.GA[(j0 + w*16 + quad*4 + r)*256 + i0 + c*16 + l15],
                    sb[(c*16 + l15)*65 + (w*16 + quad*4 + r)]);
    }
  } else if (bx < 2192) {
    // W1 = Kinv @ psi2s (fp32, 32x32 tile)
    int idx = bx - 2128;
    int col0 = (idx & 7)*32, row0 = (idx >> 3)*32;
    float* As = sb; float* Bs = sb + 1089;
    int r2 = (tid >> 4)*2, c2 = (tid & 15)*2;
    float a00=0, a01=0, a10=0, a11=0;
    int sr = tid >> 3, sq = (tid & 7)*4;
    for (int kc = 0; kc < 256; kc += 32) {
      float4 av = *(const float4*)&p.Kinv[(row0+sr)*MI + kc + sq];
      As[(sq+0)*33 + sr] = av.x; As[(sq+1)*33 + sr] = av.y;
      As[(sq+2)*33 + sr] = av.z; As[(sq+3)*33 + sr] = av.w;
      float4 bv = *(const float4*)&p.psi2s[(kc+sr)*MI + col0 + sq];
      Bs[sr*33 + sq+0] = bv.x; Bs[sr*33 + sq+1] = bv.y;
      Bs[sr*33 + sq+2] = bv.z; Bs[sr*33 + sq+3] = bv.w;
      __syncthreads();
      #pragma unroll
      for (int kk = 0; kk < 32; kk++) {
        float x0 = As[kk*33 + r2], x1 = As[kk*33 + r2 + 1];
        float y0 = Bs[kk*33 + c2], y1 = Bs[kk*33 + c2 + 1];
        a00 += x0*y0; a01 += x0*y1; a10 += x1*y0; a11 += x1*y1;
      }
      __syncthreads();
    }
    int ro = (row0 + r2)*MI + col0 + c2;
    p.W1[ro] = a00; p.W1[ro+1] = a01; p.W1[ro+MI] = a10; p.W1[ro+MI+1] = a11;
  } else if (bx < 2256) {
    // Y2T = Scov @ Kinv (fp32, 32x32 tile) -> p.W
    int idx = bx - 2192;
    int col0 = (idx & 7)*32, row0 = (idx >> 3)*32;
    float* As = sb; float* Bs = sb + 1089;
    int r2 = (tid >> 4)*2, c2 = (tid & 15)*2;
    float a00=0, a01=0, a10=0, a11=0;
    int sr = tid >> 3, sq = (tid & 7)*4;
    for (int kc = 0; kc < 256; kc += 32) {
      float4 av = *(const float4*)&p.Scov[(row0+sr)*MI + kc + sq];
      As[(sq+0)*33 + sr] = av.x; As[(sq+1)*33 + sr] = av.y;
      As[(sq+2)*33 + sr] = av.z; As[(sq+3)*33 + sr] = av.w;
      float4 bv = *(const float4*)&p.Kinv[(kc+sr)*MI + col0 + sq];
      Bs[sr*33 + sq+0] = bv.x; Bs[sr*33 + sq+1] = bv.y;
      Bs[sr*33 + sq+2] = bv.z; Bs[sr*33 + sq+3] = bv.w;
      __syncthreads();
      #pragma unroll
      for (int kk = 0; kk < 32; kk++) {
        float x0 = As[kk*33 + r2], x1 = As[kk*33 + r2 + 1];
        float y0 = Bs[kk*33 + c2], y1 = Bs[kk*33 + c2 + 1];
        a00 += x0*y0; a01 += x0*y1; a10 += x1*y0; a11 += x1*y1;
      }
      __syncthreads();
    }
    int ro = (row0 + r2)*MI + col0 + c2;
    p.W[ro] = a00; p.W[ro+1] = a01; p.W[ro+MI] = a10; p.W[ro+MI+1] = a11;
  } else if (bx < 2384) {
    // forward_mean = psi1 @ t3
    int rbase = (bx - 2256)*8;
    int c = tid & 31, r = rbase + (tid >> 5);
    float acc = 0;
    for (int k = 0; k < 256; k += 4) {
      float4 a4 = *(const float4*)&p.psi1[r*256 + k];
      acc += a4.x*p.t3[(k+0)*32+c] + a4.y*p.t3[(k+1)*32+c]
           + a4.z*p.t3[(k+2)*32+c] + a4.w*p.t3[(k+3)*32+c];
    }
    p.outMean[r*32 + c] = acc;
  } else {
    // V = psi2s @ t3
    int rbase = (bx - 2384)*8;
    int c = tid & 31, r = rbase + (tid >> 5);
    float acc = 0;
    for (int k = 0; k < 256; k += 4) {
      float4 a4 = *(const float4*)&p.psi2s[r*256 + k];
      acc += a4.x*p.t3[(k+0)*32+c] + a4.y*p.t3[(k+1)*32+c]
           + a4.z*p.t3[(k+2)*32+c] + a4.w*p.t3[(k+3)*32+c];
    }
    p.V[r*32 + c] = acc;
  }
}

// ================= Phase F =================
// [0,256) fvar (1-deep prefetch) | [256,448) 6 reduction segs + finalize
__global__ __launch_bounds__(256) void kF(Params p) {
  __shared__ float red[8];
  int bx = blockIdx.x, tid = threadIdx.x;
  if (bx < 256) {
    int lane = tid & 63, w = tid >> 6;
    int n = bx*4 + w;
    int l15 = lane & 15, quad = lane >> 4;
    floatx4 acc[2][2];
    #pragma unroll
    for (int i = 0; i < 2; i++)
      #pragma unroll
      for (int j = 0; j < 2; j++) acc[i][j] = (floatx4){0.f,0.f,0.f,0.f};
    size_t base = (size_t)n*8192;
    short8 h0 = *(const short8*)&p.tmp[base + l15*256 + quad*8];
    short8 h1 = *(const short8*)&p.tmp[base + (16 + l15)*256 + quad*8];
    #pragma unroll
    for (int s8 = 0; s8 < 8; s8++) {
      short8 h0n = h0, h1n = h1;
      if (s8 < 7) {
        int off = (s8+1)*32 + quad*8;
        h0n = *(const short8*)&p.tmp[base + l15*256 + off];
        h1n = *(const short8*)&p.tmp[base + (16 + l15)*256 + off];
      }
      acc[0][0] = __builtin_amdgcn_mfma_f32_16x16x32_bf16(h0, h0, acc[0][0], 0,0,0);
      acc[0][1] = __builtin_amdgcn_mfma_f32_16x16x32_bf16(h0, h1, acc[0][1], 0,0,0);
      acc[1][0] = __builtin_amdgcn_mfma_f32_16x16x32_bf16(h1, h0, acc[1][0], 0,0,0);
      acc[1][1] = __builtin_amdgcn_mfma_f32_16x16x32_bf16(h1, h1, acc[1][1], 0,0,0);
      h0 = h0n; h1 = h1n;
    }
    float ib = 1.f / (*p.pbeta);
    #pragma unroll
    for (int I = 0; I < 2; I++)
      #pragma unroll
      for (int J = 0; J < 2; J++)
        #pragma unroll
        for (int r = 0; r < 4; r++) {
          int row = I*16 + quad*4 + r, col = J*16 + l15;
          p.outVar[(size_t)n*1024 + row*32 + col] = acc[I][J][r] + (row == col ? ib : 0.f);
        }
  } else {
    int idx = bx - 256;
    int seg = idx >> 5;
    int i0 = (idx & 31)*256 + tid;
    const int stride = 32*256;
    float s = 0, s2 = 0;
    int target = 0;
    if (seg == 0) { for (int i = i0; i < 65536; i += stride) s += p.Kinv[i]*p.psi2s[i]; target = 0; }
    else if (seg == 1) {
      for (int i = i0; i < 8192; i += stride) { s += p.qmu[i]*p.t3[i]; s2 += p.t3[i]*p.V[i]; }
      target = 1;
    }
    else if (seg == 2) { for (int i = i0; i < 65536; i += stride) s += p.Kinv[i]*p.Scov[i]; target = 2; }
    else if (seg == 3) {
      for (int i = i0; i < MI*DOUT; i += stride) {
        int m = i >> 5, k = i & 31;
        float dq = p.qs[m*8224 + k];   // (m*256+m)*32 + k
        s += logf(dq*dq);
      }
      target = 5;
    }
    else if (seg == 4) {
      // tr(W Scov) = sum W1 . Y2T  (Y2T = Scov@Kinv in p.W)
      for (int i = i0; i < 65536; i += stride) s += p.W1[i]*p.W[i];
      target = 6;
    }
    else {
      // sum GA . (Scov + qmu qmu^T)
      for (int i = i0; i < 65536; i += stride) {
        int r = i >> 8, c = i & 255;
        float qq = 0;
        #pragma unroll
        for (int d = 0; d < DOUT; d++) qq += p.qmu[r*DOUT + d]*p.qmu[c*DOUT + d];
        s += p.GA[i]*(p.Scov[i] + qq);
      }
      target = 7;
    }
    #pragma unroll
    for (int off = 32; off >= 1; off >>= 1) s += __shfl_down(s, off, 64);
    #pragma unroll
    for (int off = 32; off >= 1; off >>= 1) s2 += __shfl_down(s2, off, 64);
    if ((tid & 63) == 0) { red[tid >> 6] = s; red[4 + (tid >> 6)] = s2; }
    __syncthreads();
    if (tid == 0) {
      float bs = red[0] + red[1] + red[2] + red[3];
      atomicAdd(&p.Sv[target], bs);
      if (seg == 1) {
        float bs2 = red[4] + red[5] + red[6] + red[7];
        atomicAdd(&p.Sv[6], bs2);   // t3 . V part of the W-term
      }
      __threadfence();
      unsigned prev = atomicAdd((unsigned int*)&p.Sv[8], 1u);
      if (prev == 191u) {
        float S0 = atomicAdd(&p.Sv[0], 0.f);
        float S1 = atomicAdd(&p.Sv[1], 0.f);
        float S2 = atomicAdd(&p.Sv[2], 0.f);
        float S5 = atomicAdd(&p.Sv[5], 0.f);
        float S6 = atomicAdd(&p.Sv[6], 0.f);
        float S7 = atomicAdd(&p.Sv[7], 0.f);
        // S4 = sum_offdiag E^2 from per-NS-tile partials (offdiag tiles x2)
        float S4 = 0;
        #pragma unroll
        for (int tt = 0; tt < 10; tt++) {
          float wgt = (tt==0 || tt==4 || tt==7 || tt==9) ? 1.f : 2.f;
          S4 += wgt * p.ep2[tt];
        }
        float v = *p.pvar, b = *p.pbeta;
        float trace = (float)N_PTS * v - S0;
        float lml = -0.5f * b * (float)DOUT * trace;
        float c = v + JITTER;
        float logdetK = (float)MI * logf(c) - 0.5f * S4;
        float kl = 0.5f*(S1 + S2 - (float)(MI*DOUT) + (float)DOUT*logdetK - S5);
        lml -= kl;
        lml -= 0.5f * b * (S6 - S7);
        p.outL[0] = lml;
      }
    }
  }
}

extern "C" void kernel_launch(void* const* d_in, const int* in_sizes, int n_in,
                              void* d_out, int out_size, void* d_ws, size_t ws_size,
                              hipStream_t stream) {
  (void)in_sizes; (void)n_in; (void)out_size; (void)ws_size;
  float* out = (float*)d_out;
  float* ws  = (float*)d_ws;

  Params p;
  p.Xm = (const float*)d_in[0];
  p.Xv = (const float*)d_in[1];
  p.Z  = (const float*)d_in[2];
  p.qmu = (const float*)d_in[3];
  p.qs  = (const float*)d_in[4];
  p.ls  = (const float*)d_in[5];
  p.pvar  = (const float*)d_in[6];
  p.pbeta = (const float*)d_in[7];
  p.psi2s = ws + OFF_PSI2S;
  p.Scov  = ws + OFF_SCOV;
  p.GA    = ws + OFF_GA;
  p.Sv    = ws + OFF_S;
  p.zarea = ws;
  p.psi1  = ws + OFF_PSI1;
  p.p1h   = (ushort*)(ws + OFF_P1H);
  p.gm    = ws + OFF_GM;
  p.f2    = ws + OFF_F2;
  p.ep2   = ws + OFF_EP2;
  p.Kinv  = ws + OFF_KINV;
  p.Kh    = (ushort*)(ws + OFF_KH);
  p.W1    = ws + OFF_W1;
  p.W     = ws + OFF_W;
  p.t3    = ws + OFF_T3;
  p.V     = ws + OFF_V;
  p.zb    = (ushort*)(ws + OFF_ZB);
  p.abf   = (ushort*)(ws + OFF_ABF);
  p.abfT  = (ushort*)(ws + OFF_ABFT);
  p.Btj   = (ushort*)(ws + OFF_BTJ);
  p.Btl   = (ushort*)(ws + OFF_BTL);
  p.tmp   = (ushort*)(ws + OFF_TMP);
  p.outMean = out;
  p.outVar  = out + 32768;
  p.outL    = out + 32768 + 1048576;

  kA<<<2419, 256, 0, stream>>>(p);
  kB<<<576, 256, 0, stream>>>(p);
  kE<<<2416, 256, 0, stream>>>(p);
  kF<<<448, 256, 0, stream>>>(p);
}

// Round 6
// 170.948 us; speedup vs baseline: 1.4004x; 1.4004x over previous
//
#include <hip/hip_runtime.h>
#include <math.h>

// HiddenLayer_20126216749058: sparse-GP layer, N=1024, Q=32, M=256, D=32.
// R12: REVERT to R10 (measured 172.88us). R11's depth-4 moved NS-Kinv into kA
//      computing E from Z directly -> 10-block tail, 1 wave/SIMD, ~85us of
//      exposed latency (kA 88us, occupancy 2.4%). NS stays in kB from
//      materialized KM (64 blocks, proven). Fill (~44us, 268MB re-poison) is
//      confirmed inside the timed path; all kernels individually <43us.

#define N_PTS 1024
#define QD 32
#define MI 256
#define DOUT 32
#define JITTER 1e-6f
#define LOG2E 1.4426950408889634f
#define LSU 40    // bf16 LDS row stride (80B)

typedef short short8 __attribute__((ext_vector_type(8)));
typedef float floatx4 __attribute__((ext_vector_type(4)));
typedef unsigned short ushort;

// ---- workspace layout (float offsets) ----
#define OFF_PSI2S 0           // 65536 zeroed (atomic)
#define OFF_SCOV  65536       // 65536 zeroed (atomic)
#define OFF_GA    131072      // 65536 zeroed (atomic)
#define OFF_S     196608      // 16 scalars zeroed; [8] = done-counter
#define ZERO_CNT  196624
#define OFF_PSI1  196624      // 262144 N*M fp32
#define OFF_P1H   458768      // 131072 N*M bf16
#define OFF_GM    589840      // 262144 N*M fp32 (LOG2E-scaled)
#define OFF_F2    851984      // 32768  N*Q fp32 (LOG2E-scaled)
#define OFF_KM    884752      // 65536
#define OFF_KINV  950288      // 65536
#define OFF_KH    1015824     // 32768  M*M bf16
#define OFF_W1    1048592     // 65536  Kinv@psi2s
#define OFF_W     1114128     // 65536  Y2T = Scov@Kinv
#define OFF_T3    1179664     // 8192   M*D
#define OFF_ZB    1187856     // 4096   M*Q bf16
#define OFF_ABF   1191952     // 131072 N*M bf16
#define OFF_ABFT  1323024     // 131072 M*N bf16
#define OFF_BTJ   1454096     // 1048576 D*M*M bf16 [d][j][l]
#define OFF_BTL   2502672     // 1048576 D*M*M bf16 [d][l][j]
#define OFF_TMP   3551248     // 4194304 N*D*M bf16 [n][d][l]
#define OFF_V     7745552     // 8192   M*D = psi2s@t3
// end = 7753744 floats = 31.0 MB

struct Params {
  const float *Xm, *Xv, *Z, *ls, *pvar, *pbeta, *qmu, *qs;
  float *psi1, *gm, *f2, *KM, *Kinv, *W1, *W, *t3, *V;
  float *psi2s, *Scov, *GA, *Sv, *zarea;
  ushort *p1h, *Kh, *zb, *abf, *abfT, *Btj, *Btl, *tmp;
  float *outMean, *outVar, *outL;
};

__device__ __forceinline__ ushort f2bf(float x) {
  unsigned int u = __builtin_bit_cast(unsigned int, x);
  u += 0x7fffu + ((u >> 16) & 1u);
  return (ushort)(u >> 16);
}

// upper-triangular 4x4 tile enumeration: t in [0,10) -> (a,b), a<=b
__device__ __forceinline__ void tile_ab(int t, int* a_, int* b_) {
  int a = (t >= 4) + (t >= 7) + (t >= 9);
  int st = (a == 0) ? 0 : (a == 1) ? 4 : (a == 2) ? 7 : 9;
  *a_ = a; *b_ = t - st + a;
}

// ================= Phase A =================
// [0,256) stats 4n/blk | [256,512) Kmm | [512,609) zero | [609,617) zb
// [617,1641) btj | [1641,2665) btl
__global__ __launch_bounds__(256) void kA(Params p) {
  __shared__ __align__(16) float sb[2112];
  int bx = blockIdx.x, tid = threadIdx.x;
  if (bx < 256) {
    int nb = bx*4;
    float* w1s  = sb;        // [4][32]
    float* w1mu = sb+128;
    float* w2s  = sb+256;
    float* w2mu = sb+384;
    float* x1a  = sb+512;    // la1+a1s
    float* x2a  = sb+640;    // 0.5*la2+a2s
    float* rl2s = sb+768;    // [32]
    float* csh  = sb+800;    // [8]: c1sh[4], c2sh[4]
    float v = *p.pvar;
    if (tid < 128) {
      int nl = tid >> 5, q = tid & 31;
      int n = nb + nl;
      float s = p.Xv[n*QD+q], mu = p.Xm[n*QD+q], l = p.ls[q], l2 = l*l;
      float rl2 = 1.f/l2;
      float d1 = l2 + s, d2 = l2 + 2.f*s;
      float iw1 = 1.f/d1, iw2 = 1.f/d2;
      w1s[nl*32+q] = iw1; w1mu[nl*32+q] = iw1*mu;
      w2s[nl*32+q] = iw2; w2mu[nl*32+q] = iw2*mu;
      x1a[nl*32+q] = logf(d1*rl2) + mu*mu*iw1;
      x2a[nl*32+q] = 0.5f*logf(d2*rl2) + mu*mu*iw2;
      if (nl == 0) rl2s[q] = rl2;
      p.f2[n*QD+q] = LOG2E*0.5f*(rl2 - iw2);
    }
    __syncthreads();
    {
      int w = tid >> 6, lane = tid & 63;
      float x1 = (lane < 32) ? x1a[w*32+lane] : 0.f;
      float x2 = (lane < 32) ? x2a[w*32+lane] : 0.f;
      #pragma unroll
      for (int o = 16; o >= 1; o >>= 1) {
        x1 += __shfl_xor(x1, o, 32);
        x2 += __shfl_xor(x2, o, 32);
      }
      if (lane == 0) { csh[w] = -0.5f*x1; csh[4+w] = 2.f*logf(v) - x2; }
    }
    __syncthreads();
    int m = tid;
    float zv[32];
    float zsq = 0;
    #pragma unroll
    for (int q4 = 0; q4 < QD; q4 += 4) {
      float4 z4 = *(const float4*)&p.Z[m*QD + q4];
      zv[q4+0]=z4.x; zv[q4+1]=z4.y; zv[q4+2]=z4.z; zv[q4+3]=z4.w;
      zsq += rl2s[q4+0]*z4.x*z4.x + rl2s[q4+1]*z4.y*z4.y
           + rl2s[q4+2]*z4.z*z4.z + rl2s[q4+3]*z4.w*z4.w;
    }
    #pragma unroll
    for (int nl = 0; nl < 4; nl++) {
      int n = nb + nl;
      float b1 = 0, c1a = 0, eb = 0, ec = 0;
      #pragma unroll
      for (int q = 0; q < QD; q++) {
        float z = zv[q], zz = z*z;
        b1 += w1mu[nl*32+q]*z; c1a += w1s[nl*32+q]*zz;
        eb += w2mu[nl*32+q]*z; ec += w2s[nl*32+q]*zz;
      }
      float pv = v * __expf(csh[nl] + b1 - 0.5f*c1a);
      p.psi1[n*MI + m] = pv;
      p.p1h[n*MI + m] = f2bf(pv);
      p.gm[n*MI + m] = LOG2E*(0.5f*csh[4+nl] + (eb - 0.25f*ec) - 0.25f*zsq);
    }
  } else if (bx < 512) {
    int m = bx - 256;
    if (tid < QD) { float l = p.ls[tid]; sb[tid] = 1.f/(l*l); }
    __syncthreads();
    int k = tid;
    float acc = 0;
    #pragma unroll
    for (int q4 = 0; q4 < QD; q4 += 4) {
      float4 zm = *(const float4*)&p.Z[m*QD + q4];
      float4 zk = *(const float4*)&p.Z[k*QD + q4];
      float d;
      d = zm.x - zk.x; acc += d*d*sb[q4+0];
      d = zm.y - zk.y; acc += d*d*sb[q4+1];
      d = zm.z - zk.z; acc += d*d*sb[q4+2];
      d = zm.w - zk.w; acc += d*d*sb[q4+3];
    }
    float v = *p.pvar;
    p.KM[m*MI + k] = v*__expf(-0.5f*acc) + (m == k ? JITTER : 0.f);
  } else if (bx < 609) {
    int base = (bx - 512)*2048 + tid*8;
    #pragma unroll
    for (int e = 0; e < 8; e++) {
      int i = base + e;
      if (i < ZERO_CNT) p.zarea[i] = 0.f;
    }
  } else if (bx < 617) {
    int i = ((bx - 609)*256 + tid)*4;
    float4 z = *(const float4*)&p.Z[i];
    uint2 o;
    o.x = (unsigned)f2bf(z.x) | ((unsigned)f2bf(z.y) << 16);
    o.y = (unsigned)f2bf(z.z) | ((unsigned)f2bf(z.w) << 16);
    *(uint2*)&p.zb[i] = o;
  } else if (bx < 1641) {
    int idx = bx - 617;
    int j = idx & 255, l0 = (idx >> 8)*64;
    int base = j*8192 + l0*32;
    #pragma unroll
    for (int e = 0; e < 8; e++) {
      int lin = e*256 + tid;
      sb[(lin >> 5)*33 + (lin & 31)] = p.qs[base + lin];
    }
    __syncthreads();
    int ll = tid & 63, kq = tid >> 6;
    int l = l0 + ll;
    #pragma unroll
    for (int w8 = 0; w8 < 8; w8++) {
      int k = kq*8 + w8;
      float v = (l <= j) ? sb[ll*33 + k] : 0.f;
      p.Btj[k*65536 + j*256 + l] = f2bf(v);
    }
  } else {
    int idx = bx - 1641;
    int l = idx & 255, j0 = (idx >> 8)*64;
    {
      int jr = tid >> 2, d8 = (tid & 3)*8;
      const float* src = &p.qs[(j0+jr)*8192 + l*32 + d8];
      float4 a = *(const float4*)src, b = *(const float4*)(src+4);
      float* dst = &sb[jr*33 + d8];
      dst[0]=a.x; dst[1]=a.y; dst[2]=a.z; dst[3]=a.w;
      dst[4]=b.x; dst[5]=b.y; dst[6]=b.z; dst[7]=b.w;
    }
    __syncthreads();
    int d = tid >> 3, j8 = (tid & 7)*8;
    unsigned int pk[4];
    #pragma unroll
    for (int q = 0; q < 4; q++) {
      int ja = j0 + j8 + q*2;
      float va = (l <= ja)   ? sb[(j8 + q*2)*33 + d]     : 0.f;
      float vb = (l <= ja+1) ? sb[(j8 + q*2 + 1)*33 + d] : 0.f;
      pk[q] = (unsigned)f2bf(va) | ((unsigned)f2bf(vb) << 16);
    }
    *(uint4*)&p.Btl[d*65536 + l*256 + j0 + j8] = make_uint4(pk[0], pk[1], pk[2], pk[3]);
  }
}

// ================= Phase B =================
// [0,320) psi2 upper tiles | [320,384) NS Kinv | [384,544) scov (10 t x 16 d-grp of 2)
__global__ __launch_bounds__(256) void kB(Params p) {
  __shared__ __align__(16) float sb[4160];
  int bx = blockIdx.x, tid = threadIdx.x;
  int lane = tid & 63, w = tid >> 6, l15 = lane & 15, quad = lane >> 4;
  if (bx < 320) {
    int t = bx % 10, chunk = bx / 10;
    int a, b; tile_ab(t, &a, &b);
    int tm = a*64, tk = b*64;
    int n0 = chunk*32;
    float zm[8];
    {
      const float* zr = &p.Z[(tm + w*16 + l15)*32 + quad*8];
      float4 aq = *(const float4*)zr, bq = *(const float4*)(zr + 4);
      zm[0]=aq.x; zm[1]=aq.y; zm[2]=aq.z; zm[3]=aq.w;
      zm[4]=bq.x; zm[5]=bq.y; zm[6]=bq.z; zm[7]=bq.w;
    }
    short8 bfr[4];
    #pragma unroll
    for (int c = 0; c < 4; c++)
      bfr[c] = *(const short8*)&p.zb[(tk + c*16 + l15)*32 + quad*8];
    float accs[4][4] = {};
    #pragma unroll 2
    for (int nl = 0; nl < 32; nl++) {
      int n = n0 + nl;
      const float* fp = &p.f2[n*32 + quad*8];
      float4 f0 = *(const float4*)fp, f1 = *(const float4*)(fp + 4);
      unsigned q0 = (unsigned)f2bf(f0.x*zm[0]) | ((unsigned)f2bf(f0.y*zm[1]) << 16);
      unsigned q1 = (unsigned)f2bf(f0.z*zm[2]) | ((unsigned)f2bf(f0.w*zm[3]) << 16);
      unsigned q2 = (unsigned)f2bf(f1.x*zm[4]) | ((unsigned)f2bf(f1.y*zm[5]) << 16);
      unsigned q3 = (unsigned)f2bf(f1.z*zm[6]) | ((unsigned)f2bf(f1.w*zm[7]) << 16);
      uint4 u4 = make_uint4(q0, q1, q2, q3);
      short8 af = __builtin_bit_cast(short8, u4);
      float4 gmv = *(const float4*)&p.gm[n*256 + tm + w*16 + quad*4];
      float gmr[4] = {gmv.x, gmv.y, gmv.z, gmv.w};
      #pragma unroll
      for (int c = 0; c < 4; c++) {
        floatx4 zz = {0.f, 0.f, 0.f, 0.f};
        floatx4 g = __builtin_amdgcn_mfma_f32_16x16x32_bf16(af, bfr[c], zz, 0, 0, 0);
        float gk = p.gm[n*256 + tk + c*16 + l15];
        #pragma unroll
        for (int r = 0; r < 4; r++)
          accs[c][r] += __builtin_exp2f(g[r] + gmr[r] + gk);
      }
    }
    #pragma unroll
    for (int c = 0; c < 4; c++)
      #pragma unroll
      for (int r = 0; r < 4; r++)
        atomicAdd(&p.psi2s[(tm + w*16 + quad*4 + r)*256 + tk + c*16 + l15], accs[c][r]);
    if (tm != tk) {
      #pragma unroll
      for (int c = 0; c < 4; c++)
        #pragma unroll
        for (int r = 0; r < 4; r++)
          sb[(w*16 + quad*4 + r)*65 + c*16 + l15] = accs[c][r];
      __syncthreads();
      #pragma unroll
      for (int c = 0; c < 4; c++)
        #pragma unroll
        for (int r = 0; r < 4; r++)
          atomicAdd(&p.psi2s[(tk + w*16 + quad*4 + r)*256 + tm + c*16 + l15],
                    sb[(c*16 + l15)*65 + (w*16 + quad*4 + r)]);
    }
  } else if (bx < 384) {
    // G = E@E (E = s*KM - I), epilogue Kinv = s*(2I - s*KM + G), Kh = bf16(Kinv)
    int idx = bx - 320;
    int col0 = (idx & 7)*32, row0 = (idx >> 3)*32;
    float s = 1.f/(p.pvar[0] + JITTER);
    float* As = sb; float* Bs = sb + 1056;
    int r2 = (tid >> 4)*2, c2 = (tid & 15)*2;
    float a00=0, a01=0, a10=0, a11=0;
    int sr = tid >> 3, sq = (tid & 7)*4;
    for (int kc = 0; kc < 256; kc += 32) {
      int ar = row0 + sr;
      float4 av = *(const float4*)&p.KM[ar*MI + kc + sq];
      av.x = s*av.x - (ar == kc+sq+0 ? 1.f : 0.f);
      av.y = s*av.y - (ar == kc+sq+1 ? 1.f : 0.f);
      av.z = s*av.z - (ar == kc+sq+2 ? 1.f : 0.f);
      av.w = s*av.w - (ar == kc+sq+3 ? 1.f : 0.f);
      As[(sq+0)*33 + sr] = av.x; As[(sq+1)*33 + sr] = av.y;
      As[(sq+2)*33 + sr] = av.z; As[(sq+3)*33 + sr] = av.w;
      int br = kc + sr;
      float4 bv = *(const float4*)&p.KM[br*MI + col0 + sq];
      bv.x = s*bv.x - (br == col0+sq+0 ? 1.f : 0.f);
      bv.y = s*bv.y - (br == col0+sq+1 ? 1.f : 0.f);
      bv.z = s*bv.z - (br == col0+sq+2 ? 1.f : 0.f);
      bv.w = s*bv.w - (br == col0+sq+3 ? 1.f : 0.f);
      Bs[sr*33 + sq+0] = bv.x; Bs[sr*33 + sq+1] = bv.y;
      Bs[sr*33 + sq+2] = bv.z; Bs[sr*33 + sq+3] = bv.w;
      __syncthreads();
      #pragma unroll
      for (int kk = 0; kk < 32; kk++) {
        float x0 = As[kk*33 + r2], x1 = As[kk*33 + r2 + 1];
        float y0 = Bs[kk*33 + c2], y1 = Bs[kk*33 + c2 + 1];
        a00 += x0*y0; a01 += x0*y1; a10 += x1*y0; a11 += x1*y1;
      }
      __syncthreads();
    }
    float vals[2][2] = {{a00, a01}, {a10, a11}};
    #pragma unroll
    for (int i = 0; i < 2; i++)
      #pragma unroll
      for (int j = 0; j < 2; j++) {
        int R = row0 + r2 + i, C = col0 + c2 + j;
        float kv = s*(vals[i][j] + (R == C ? 2.f : 0.f) - s*p.KM[R*MI + C]);
        p.Kinv[R*MI + C] = kv;
        p.Kh[R*MI + C] = f2bf(kv);
      }
  } else {
    // Scov upper tiles, d-groups of 2, k-loop bounded (Btj[d][i][l]=0 for l>i)
    int idx = bx - 384;
    int t = idx % 10;
    int a, b; tile_ab(t, &a, &b);
    int i0 = a*64, j0 = b*64;
    int d0 = (idx / 10)*2;
    int kend = (a + 1)*64;
    ushort* Au = (ushort*)sb; ushort* Bu = Au + 2560;
    floatx4 accs[4];
    #pragma unroll
    for (int c = 0; c < 4; c++) accs[c] = (floatx4){0.f,0.f,0.f,0.f};
    int sr = tid >> 2, sq = (tid & 3)*8;
    for (int dd = 0; dd < 2; dd++) {
      const ushort* base = p.Btj + (size_t)(d0 + dd)*65536;
      for (int kc = 0; kc < kend; kc += 32) {
        __syncthreads();
        *(uint4*)&Au[sr*LSU + sq] = *(const uint4*)&base[(i0+sr)*256 + kc + sq];
        *(uint4*)&Bu[sr*LSU + sq] = *(const uint4*)&base[(j0+sr)*256 + kc + sq];
        __syncthreads();
        short8 af = *(const short8*)&Au[(w*16 + l15)*LSU + quad*8];
        #pragma unroll
        for (int c = 0; c < 4; c++) {
          short8 bfv = *(const short8*)&Bu[(c*16 + l15)*LSU + quad*8];
          accs[c] = __builtin_amdgcn_mfma_f32_16x16x32_bf16(af, bfv, accs[c], 0, 0, 0);
        }
      }
    }
    #pragma unroll
    for (int c = 0; c < 4; c++)
      #pragma unroll
      for (int r = 0; r < 4; r++)
        atomicAdd(&p.Scov[(i0 + w*16 + quad*4 + r)*256 + j0 + c*16 + l15], accs[c][r]);
    if (i0 != j0) {
      __syncthreads();
      #pragma unroll
      for (int c = 0; c < 4; c++)
        #pragma unroll
        for (int r = 0; r < 4; r++)
          sb[(w*16 + quad*4 + r)*65 + c*16 + l15] = accs[c][r];
      __syncthreads();
      #pragma unroll
      for (int c = 0; c < 4; c++)
        #pragma unroll
        for (int r = 0; r < 4; r++)
          atomicAdd(&p.Scov[(j0 + w*16 + quad*4 + r)*256 + i0 + c*16 + l15],
                    sb[(c*16 + l15)*65 + (w*16 + quad*4 + r)]);
    }
  }
}

// ================= Phase D =================
// [0,64) abf = psi1@Kinv | [64,96) t3 = Kinv@qmu | [96,160) W1 = Kinv@psi2s
// [160,224) Y2T = Scov@Kinv  (stored in p.W)
__global__ __launch_bounds__(256) void kD(Params p) {
  __shared__ __align__(16) float sb[2560];
  int bx = blockIdx.x, tid = threadIdx.x;
  if (bx < 64) {
    int j0 = (bx & 3)*64, n0 = (bx >> 2)*64;
    int lane = tid & 63, w = tid >> 6, l15 = lane & 15, quad = lane >> 4;
    ushort* Ah = (ushort*)sb; ushort* Bh = Ah + 2560;
    floatx4 acc[4];
    #pragma unroll
    for (int c = 0; c < 4; c++) acc[c] = (floatx4){0.f,0.f,0.f,0.f};
    int sr = tid >> 2, sq = (tid & 3)*8;
    for (int kc = 0; kc < 256; kc += 32) {
      __syncthreads();
      *(uint4*)&Ah[sr*LSU + sq] = *(const uint4*)&p.p1h[(n0+sr)*256 + kc + sq];
      *(uint4*)&Bh[sr*LSU + sq] = *(const uint4*)&p.Kh[(j0+sr)*256 + kc + sq];
      __syncthreads();
      short8 ah = *(const short8*)&Ah[(w*16 + l15)*LSU + quad*8];
      #pragma unroll
      for (int c = 0; c < 4; c++) {
        short8 bh = *(const short8*)&Bh[(c*16 + l15)*LSU + quad*8];
        acc[c] = __builtin_amdgcn_mfma_f32_16x16x32_bf16(ah, bh, acc[c], 0, 0, 0);
      }
    }
    #pragma unroll
    for (int c = 0; c < 4; c++)
      #pragma unroll
      for (int r = 0; r < 4; r++) {
        int n = n0 + w*16 + quad*4 + r, j = j0 + c*16 + l15;
        ushort hv = f2bf(acc[c][r]);
        p.abf[n*256 + j] = hv;
        p.abfT[j*1024 + n] = hv;
      }
  } else if (bx < 96) {
    int rbase = (bx - 64)*8;
    int c = tid & 31, r = rbase + (tid >> 5);
    float acc = 0;
    for (int k = 0; k < 256; k += 4) {
      float4 a4 = *(const float4*)&p.Kinv[r*256 + k];
      acc += a4.x*p.qmu[(k+0)*32+c] + a4.y*p.qmu[(k+1)*32+c]
           + a4.z*p.qmu[(k+2)*32+c] + a4.w*p.qmu[(k+3)*32+c];
    }
    p.t3[r*32 + c] = acc;
  } else if (bx < 160) {
    // W1 = Kinv @ psi2s (fp32, 32x32 tile)
    int idx = bx - 96;
    int col0 = (idx & 7)*32, row0 = (idx >> 3)*32;
    float* As = sb; float* Bs = sb + 1089;
    int r2 = (tid >> 4)*2, c2 = (tid & 15)*2;
    float a00=0, a01=0, a10=0, a11=0;
    int sr = tid >> 3, sq = (tid & 7)*4;
    for (int kc = 0; kc < 256; kc += 32) {
      float4 av = *(const float4*)&p.Kinv[(row0+sr)*MI + kc + sq];
      As[(sq+0)*33 + sr] = av.x; As[(sq+1)*33 + sr] = av.y;
      As[(sq+2)*33 + sr] = av.z; As[(sq+3)*33 + sr] = av.w;
      float4 bv = *(const float4*)&p.psi2s[(kc+sr)*MI + col0 + sq];
      Bs[sr*33 + sq+0] = bv.x; Bs[sr*33 + sq+1] = bv.y;
      Bs[sr*33 + sq+2] = bv.z; Bs[sr*33 + sq+3] = bv.w;
      __syncthreads();
      #pragma unroll
      for (int kk = 0; kk < 32; kk++) {
        float x0 = As[kk*33 + r2], x1 = As[kk*33 + r2 + 1];
        float y0 = Bs[kk*33 + c2], y1 = Bs[kk*33 + c2 + 1];
        a00 += x0*y0; a01 += x0*y1; a10 += x1*y0; a11 += x1*y1;
      }
      __syncthreads();
    }
    int ro = (row0 + r2)*MI + col0 + c2;
    p.W1[ro] = a00; p.W1[ro+1] = a01; p.W1[ro+MI] = a10; p.W1[ro+MI+1] = a11;
  } else {
    // Y2T = Scov @ Kinv (fp32, 32x32 tile) -> p.W
    int idx = bx - 160;
    int col0 = (idx & 7)*32, row0 = (idx >> 3)*32;
    float* As = sb; float* Bs = sb + 1089;
    int r2 = (tid >> 4)*2, c2 = (tid & 15)*2;
    float a00=0, a01=0, a10=0, a11=0;
    int sr = tid >> 3, sq = (tid & 7)*4;
    for (int kc = 0; kc < 256; kc += 32) {
      float4 av = *(const float4*)&p.Scov[(row0+sr)*MI + kc + sq];
      As[(sq+0)*33 + sr] = av.x; As[(sq+1)*33 + sr] = av.y;
      As[(sq+2)*33 + sr] = av.z; As[(sq+3)*33 + sr] = av.w;
      float4 bv = *(const float4*)&p.Kinv[(kc+sr)*MI + col0 + sq];
      Bs[sr*33 + sq+0] = bv.x; Bs[sr*33 + sq+1] = bv.y;
      Bs[sr*33 + sq+2] = bv.z; Bs[sr*33 + sq+3] = bv.w;
      __syncthreads();
      #pragma unroll
      for (int kk = 0; kk < 32; kk++) {
        float x0 = As[kk*33 + r2], x1 = As[kk*33 + r2 + 1];
        float y0 = Bs[kk*33 + c2], y1 = Bs[kk*33 + c2 + 1];
        a00 += x0*y0; a01 += x0*y1; a10 += x1*y0; a11 += x1*y1;
      }
      __syncthreads();
    }
    int ro = (row0 + r2)*MI + col0 + c2;
    p.W[ro] = a00; p.W[ro+1] = a01; p.W[ro+MI] = a10; p.W[ro+MI+1] = a11;
  }
}

// ================= Phase E =================
// [0,2048) tmp GEMM, l0-interleaved block map (resident sets mix durations)
// [2048,2128) GA gram upper (10 t x 8 n-chunks of 128, mirror via LDS T)
// [2128,2256) fmean | [2256,2288) V = psi2s @ t3
__global__ __launch_bounds__(256) void kE(Params p) {
  __shared__ __align__(16) float sb[4160];
  int bx = blockIdx.x, tid = threadIdx.x;
  int lane = tid & 63, w = tid >> 6, l15 = lane & 15, quad = lane >> 4;
  if (bx < 2048) {
    // block map: l0 class from bits >=8 so stride-256 resident sets mix 8/6/4/2-step blocks
    int u = bx & 255, vv = bx >> 8;
    int n0 = (u & 15)*64;
    int dgl = (u >> 4) | ((vv >> 2) << 4);   // d in [0,32)
    int l0c = vv & 3;
    int c0 = dgl*256 + l0c*64;               // flat col base over (d,l)
    int l0 = l0c*64;                         // cols j<l0 of Btl rows are zero
    ushort* As = (ushort*)sb; ushort* Bs = As + 2560;
    floatx4 acc[4];
    #pragma unroll
    for (int c = 0; c < 4; c++) acc[c] = (floatx4){0.f,0.f,0.f,0.f};
    int sr = tid >> 2, sq = (tid & 3)*8;
    for (int kc = l0; kc < 256; kc += 32) {
      __syncthreads();
      *(uint4*)&As[sr*LSU + sq] = *(const uint4*)&p.abf[(n0+sr)*256 + kc + sq];
      *(uint4*)&Bs[sr*LSU + sq] = *(const uint4*)&p.Btl[(size_t)(c0+sr)*256 + kc + sq];
      __syncthreads();
      short8 af = *(const short8*)&As[(w*16 + l15)*LSU + quad*8];
      #pragma unroll
      for (int c = 0; c < 4; c++) {
        short8 b = *(const short8*)&Bs[(c*16 + l15)*LSU + quad*8];
        acc[c] = __builtin_amdgcn_mfma_f32_16x16x32_bf16(af, b, acc[c], 0, 0, 0);
      }
    }
    #pragma unroll
    for (int c = 0; c < 4; c++)
      #pragma unroll
      for (int r = 0; r < 4; r++) {
        int n = n0 + w*16 + quad*4 + r, cc = c0 + c*16 + l15;
        p.tmp[(size_t)n*8192 + cc] = f2bf(acc[c][r]);
      }
  } else if (bx < 2128) {
    // GA = abf^T abf, symmetric: upper tiles + mirror, 8 n-chunks of 128
    int idx = bx - 2048;
    int t = idx % 10;
    int a, b; tile_ab(t, &a, &b);
    int i0 = a*64, j0 = b*64;
    int nc0 = (idx / 10)*128;
    ushort* Au = (ushort*)sb; ushort* Bu = Au + 2560;
    floatx4 accs[4];
    #pragma unroll
    for (int c = 0; c < 4; c++) accs[c] = (floatx4){0.f,0.f,0.f,0.f};
    int sr = tid >> 2, sq = (tid & 3)*8;
    for (int kc = 0; kc < 128; kc += 32) {
      __syncthreads();
      *(uint4*)&Au[sr*LSU + sq] = *(const uint4*)&p.abfT[(i0+sr)*1024 + nc0 + kc + sq];
      *(uint4*)&Bu[sr*LSU + sq] = *(const uint4*)&p.abfT[(j0+sr)*1024 + nc0 + kc + sq];
      __syncthreads();
      short8 af = *(const short8*)&Au[(w*16 + l15)*LSU + quad*8];
      #pragma unroll
      for (int c = 0; c < 4; c++) {
        short8 bfv = *(const short8*)&Bu[(c*16 + l15)*LSU + quad*8];
        accs[c] = __builtin_amdgcn_mfma_f32_16x16x32_bf16(af, bfv, accs[c], 0, 0, 0);
      }
    }
    #pragma unroll
    for (int c = 0; c < 4; c++)
      #pragma unroll
      for (int r = 0; r < 4; r++)
        atomicAdd(&p.GA[(i0 + w*16 + quad*4 + r)*256 + j0 + c*16 + l15], accs[c][r]);
    if (i0 != j0) {
      __syncthreads();
      #pragma unroll
      for (int c = 0; c < 4; c++)
        #pragma unroll
        for (int r = 0; r < 4; r++)
          sb[(w*16 + quad*4 + r)*65 + c*16 + l15] = accs[c][r];
      __syncthreads();
      #pragma unroll
      for (int c = 0; c < 4; c++)
        #pragma unroll
        for (int r = 0; r < 4; r++)
          atomicAdd(&p.GA[(j0 + w*16 + quad*4 + r)*256 + i0 + c*16 + l15],
                    sb[(c*16 + l15)*65 + (w*16 + quad*4 + r)]);
    }
  } else if (bx < 2256) {
    // forward_mean = psi1 @ t3
    int rbase = (bx - 2128)*8;
    int c = tid & 31, r = rbase + (tid >> 5);
    float acc = 0;
    for (int k = 0; k < 256; k += 4) {
      float4 a4 = *(const float4*)&p.psi1[r*256 + k];
      acc += a4.x*p.t3[(k+0)*32+c] + a4.y*p.t3[(k+1)*32+c]
           + a4.z*p.t3[(k+2)*32+c] + a4.w*p.t3[(k+3)*32+c];
    }
    p.outMean[r*32 + c] = acc;
  } else {
    // V = psi2s @ t3
    int rbase = (bx - 2256)*8;
    int c = tid & 31, r = rbase + (tid >> 5);
    float acc = 0;
    for (int k = 0; k < 256; k += 4) {
      float4 a4 = *(const float4*)&p.psi2s[r*256 + k];
      acc += a4.x*p.t3[(k+0)*32+c] + a4.y*p.t3[(k+1)*32+c]
           + a4.z*p.t3[(k+2)*32+c] + a4.w*p.t3[(k+3)*32+c];
    }
    p.V[r*32 + c] = acc;
  }
}

// ================= Phase F =================
// [0,256) fvar (1-deep prefetch pipeline) | [256,480) reductions + finalize
__global__ __launch_bounds__(256) void kF(Params p) {
  __shared__ float red[8];
  int bx = blockIdx.x, tid = threadIdx.x;
  if (bx < 256) {
    int lane = tid & 63, w = tid >> 6;
    int n = bx*4 + w;
    int l15 = lane & 15, quad = lane >> 4;
    floatx4 acc[2][2];
    #pragma unroll
    for (int i = 0; i < 2; i++)
      #pragma unroll
      for (int j = 0; j < 2; j++) acc[i][j] = (floatx4){0.f,0.f,0.f,0.f};
    size_t base = (size_t)n*8192;
    short8 h0 = *(const short8*)&p.tmp[base + l15*256 + quad*8];
    short8 h1 = *(const short8*)&p.tmp[base + (16 + l15)*256 + quad*8];
    #pragma unroll
    for (int s8 = 0; s8 < 8; s8++) {
      short8 h0n = h0, h1n = h1;
      if (s8 < 7) {
        int off = (s8+1)*32 + quad*8;
        h0n = *(const short8*)&p.tmp[base + l15*256 + off];
        h1n = *(const short8*)&p.tmp[base + (16 + l15)*256 + off];
      }
      acc[0][0] = __builtin_amdgcn_mfma_f32_16x16x32_bf16(h0, h0, acc[0][0], 0,0,0);
      acc[0][1] = __builtin_amdgcn_mfma_f32_16x16x32_bf16(h0, h1, acc[0][1], 0,0,0);
      acc[1][0] = __builtin_amdgcn_mfma_f32_16x16x32_bf16(h1, h0, acc[1][0], 0,0,0);
      acc[1][1] = __builtin_amdgcn_mfma_f32_16x16x32_bf16(h1, h1, acc[1][1], 0,0,0);
      h0 = h0n; h1 = h1n;
    }
    float ib = 1.f / (*p.pbeta);
    #pragma unroll
    for (int I = 0; I < 2; I++)
      #pragma unroll
      for (int J = 0; J < 2; J++)
        #pragma unroll
        for (int r = 0; r < 4; r++) {
          int row = I*16 + quad*4 + r, col = J*16 + l15;
          p.outVar[(size_t)n*1024 + row*32 + col] = acc[I][J][r] + (row == col ? ib : 0.f);
        }
  } else {
    int idx = bx - 256;
    int seg = idx >> 5;
    int i0 = (idx & 31)*256 + tid;
    const int stride = 32*256;
    float s = 0, s2 = 0;
    int target = 0;
    if (seg == 0) { for (int i = i0; i < 65536; i += stride) s += p.Kinv[i]*p.psi2s[i]; target = 0; }
    else if (seg == 1) {
      for (int i = i0; i < 8192; i += stride) { s += p.qmu[i]*p.t3[i]; s2 += p.t3[i]*p.V[i]; }
      target = 1;
    }
    else if (seg == 2) { for (int i = i0; i < 65536; i += stride) s += p.Kinv[i]*p.Scov[i]; target = 2; }
    else if (seg == 3) {
      float invc = 1.f/(*p.pvar + JITTER);
      for (int i = i0; i < 65536; i += stride) {
        int r = i >> 8, c = i & 255;
        if (r != c) { float e = p.KM[i]*invc; s += e*e; }
      }
      target = 4;
    }
    else if (seg == 4) {
      for (int i = i0; i < MI*DOUT; i += stride) {
        int m = i >> 5, k = i & 31;
        float dq = p.qs[m*8224 + k];   // (m*256+m)*32 + k
        s += logf(dq*dq);
      }
      target = 5;
    }
    else if (seg == 5) {
      // tr(W Scov) = sum W1 . Y2T  (Y2T = Scov@Kinv in p.W)
      for (int i = i0; i < 65536; i += stride) s += p.W1[i]*p.W[i];
      target = 6;
    }
    else {
      // sum GA . (Scov + qmu qmu^T)
      for (int i = i0; i < 65536; i += stride) {
        int r = i >> 8, c = i & 255;
        float qq = 0;
        #pragma unroll
        for (int d = 0; d < DOUT; d++) qq += p.qmu[r*DOUT + d]*p.qmu[c*DOUT + d];
        s += p.GA[i]*(p.Scov[i] + qq);
      }
      target = 7;
    }
    #pragma unroll
    for (int off = 32; off >= 1; off >>= 1) s += __shfl_down(s, off, 64);
    #pragma unroll
    for (int off = 32; off >= 1; off >>= 1) s2 += __shfl_down(s2, off, 64);
    if ((tid & 63) == 0) { red[tid >> 6] = s; red[4 + (tid >> 6)] = s2; }
    __syncthreads();
    if (tid == 0) {
      float bs = red[0] + red[1] + red[2] + red[3];
      atomicAdd(&p.Sv[target], bs);
      if (seg == 1) {
        float bs2 = red[4] + red[5] + red[6] + red[7];
        atomicAdd(&p.Sv[6], bs2);   // t3 . V part of the W-term
      }
      __threadfence();
      unsigned prev = atomicAdd((unsigned int*)&p.Sv[8], 1u);
      if (prev == 223u) {
        float S0 = atomicAdd(&p.Sv[0], 0.f);
        float S1 = atomicAdd(&p.Sv[1], 0.f);
        float S2 = atomicAdd(&p.Sv[2], 0.f);
        float S4 = atomicAdd(&p.Sv[4], 0.f);
        float S5 = atomicAdd(&p.Sv[5], 0.f);
        float S6 = atomicAdd(&p.Sv[6], 0.f);
        float S7 = atomicAdd(&p.Sv[7], 0.f);
        float v = *p.pvar, b = *p.pbeta;
        float trace = (float)N_PTS * v - S0;
        float lml = -0.5f * b * (float)DOUT * trace;
        float c = v + JITTER;
        float logdetK = (float)MI * logf(c) - 0.5f * S4;
        float kl = 0.5f*(S1 + S2 - (float)(MI*DOUT) + (float)DOUT*logdetK - S5);
        lml -= kl;
        lml -= 0.5f * b * (S6 - S7);
        p.outL[0] = lml;
      }
    }
  }
}

extern "C" void kernel_launch(void* const* d_in, const int* in_sizes, int n_in,
                              void* d_out, int out_size, void* d_ws, size_t ws_size,
                              hipStream_t stream) {
  (void)in_sizes; (void)n_in; (void)out_size; (void)ws_size;
  float* out = (float*)d_out;
  float* ws  = (float*)d_ws;

  Params p;
  p.Xm = (const float*)d_in[0];
  p.Xv = (const float*)d_in[1];
  p.Z  = (const float*)d_in[2];
  p.qmu = (const float*)d_in[3];
  p.qs  = (const float*)d_in[4];
  p.ls  = (const float*)d_in[5];
  p.pvar  = (const float*)d_in[6];
  p.pbeta = (const float*)d_in[7];
  p.psi2s = ws + OFF_PSI2S;
  p.Scov  = ws + OFF_SCOV;
  p.GA    = ws + OFF_GA;
  p.Sv    = ws + OFF_S;
  p.zarea = ws;
  p.psi1  = ws + OFF_PSI1;
  p.p1h   = (ushort*)(ws + OFF_P1H);
  p.gm    = ws + OFF_GM;
  p.f2    = ws + OFF_F2;
  p.KM    = ws + OFF_KM;
  p.Kinv  = ws + OFF_KINV;
  p.Kh    = (ushort*)(ws + OFF_KH);
  p.W1    = ws + OFF_W1;
  p.W     = ws + OFF_W;
  p.t3    = ws + OFF_T3;
  p.V     = ws + OFF_V;
  p.zb    = (ushort*)(ws + OFF_ZB);
  p.abf   = (ushort*)(ws + OFF_ABF);
  p.abfT  = (ushort*)(ws + OFF_ABFT);
  p.Btj   = (ushort*)(ws + OFF_BTJ);
  p.Btl   = (ushort*)(ws + OFF_BTL);
  p.tmp   = (ushort*)(ws + OFF_TMP);
  p.outMean = out;
  p.outVar  = out + 32768;
  p.outL    = out + 32768 + 1048576;

  kA<<<2665, 256, 0, stream>>>(p);
  kB<<<544, 256, 0, stream>>>(p);
  kD<<<224, 256, 0, stream>>>(p);
  kE<<<2288, 256, 0, stream>>>(p);
  kF<<<480, 256, 0, stream>>>(p);
}